// Round 1
// baseline (529.277 us; speedup 1.0000x reference)
//
#include <hip/hip_runtime.h>

constexpr int NFEA = 256;
constexpr int MID  = 128;
constexpr int H1N  = 64;
constexpr int H2N  = 32;
constexpr int H3N  = 16;

__device__ __forceinline__ float fast_tanh(float x) {
    // tanh(x) = 1 - 2/(exp(2x)+1); exp overflow/underflow give correct +-1
    float e = __expf(2.0f * x);
    float r = __builtin_amdgcn_rcpf(e + 1.0f);
    return fmaf(-2.0f, r, 1.0f);
}

// ---------------------------------------------------------------------------
// Precompute P,Q,R,S (16x16 each) into d_ws:
//   dot(l_i, M, r_j) = oL_i*oR_j*P[i][j] + oL_i*Q[i][j] + oR_j*R[i][j] + S[i][j]
// where l_i = oL_i*W_emb[i] + b_emb[i],  r_j = oR_j*W_emb[16+j] + b_emb[16+j].
// Layout: pqrs[0..255]=P (j*16+i), [256..511]=Q, [512..767]=R, [768..1023]=S.
// ---------------------------------------------------------------------------
__global__ void pqrs_kernel(const float* __restrict__ W_emb,
                            const float* __restrict__ b_emb,
                            const float* __restrict__ M,
                            float* __restrict__ pqrs) {
    const int t = threadIdx.x;
    if (t >= 256) return;
    const int j = t >> 4;   // right channel 16+j
    const int i = t & 15;   // left channel i

    float mr[8], mb[8];
    #pragma unroll
    for (int e = 0; e < 8; ++e) {
        float ar = 0.f, ab = 0.f;
        #pragma unroll
        for (int f = 0; f < 8; ++f) {
            const float m = M[e * 8 + f];
            ar = fmaf(m, W_emb[(16 + j) * 8 + f], ar);
            ab = fmaf(m, b_emb[(16 + j) * 8 + f], ab);
        }
        mr[e] = ar; mb[e] = ab;
    }
    float P = 0.f, Q = 0.f, R = 0.f, S = 0.f;
    #pragma unroll
    for (int e = 0; e < 8; ++e) {
        const float lw = W_emb[i * 8 + e];
        const float lb = b_emb[i * 8 + e];
        P = fmaf(lw, mr[e], P);
        Q = fmaf(lw, mb[e], Q);
        R = fmaf(lb, mr[e], R);
        S = fmaf(lb, mb[e], S);
    }
    pqrs[0 * 256 + j * 16 + i] = P;
    pqrs[1 * 256 + j * 16 + i] = Q;
    pqrs[2 * 256 + j * 16 + i] = R;
    pqrs[3 * 256 + j * 16 + i] = S;
}

// ---------------------------------------------------------------------------
// Per-thread 3-layer tower. Weight indices are thread-uniform -> s_load.
// All register arrays statically indexed (mandatory unrolls).
// ---------------------------------------------------------------------------
__device__ __forceinline__ void tower(const float* __restrict__ xs,
    const float* __restrict__ W1, const float* __restrict__ b1,
    const float* __restrict__ W2, const float* __restrict__ b2,
    const float* __restrict__ W3, const float* __restrict__ b3,
    float* __restrict__ h3out) {
    float h1[H1N];
    #pragma unroll
    for (int j = 0; j < H1N; ++j) h1[j] = b1[j];
    #pragma unroll 1
    for (int k0 = 0; k0 < MID; k0 += 8) {
        float xv[8];
        #pragma unroll
        for (int q = 0; q < 2; ++q) {
            const float4 v = *reinterpret_cast<const float4*>(xs + k0 + q * 4);
            xv[q * 4 + 0] = v.x; xv[q * 4 + 1] = v.y;
            xv[q * 4 + 2] = v.z; xv[q * 4 + 3] = v.w;
        }
        #pragma unroll
        for (int kk = 0; kk < 8; ++kk) {
            const float xk = xv[kk];
            const float* __restrict__ wr = W1 + (k0 + kk) * H1N;
            #pragma unroll
            for (int j = 0; j < H1N; ++j) h1[j] = fmaf(xk, wr[j], h1[j]);
        }
    }
    #pragma unroll
    for (int j = 0; j < H1N; ++j) h1[j] = fmaxf(h1[j], 0.f);

    float h2[H2N];
    #pragma unroll
    for (int j = 0; j < H2N; ++j) h2[j] = b2[j];
    #pragma unroll 4
    for (int k = 0; k < H1N; ++k) {
        const float hk = h1[k];
        const float* __restrict__ wr = W2 + k * H2N;
        #pragma unroll
        for (int j = 0; j < H2N; ++j) h2[j] = fmaf(hk, wr[j], h2[j]);
    }
    #pragma unroll
    for (int j = 0; j < H2N; ++j) h2[j] = fmaxf(h2[j], 0.f);

    #pragma unroll
    for (int j = 0; j < H3N; ++j) h3out[j] = b3[j];
    #pragma unroll 4
    for (int k = 0; k < H2N; ++k) {
        const float hk = h2[k];
        const float* __restrict__ wr = W3 + k * H3N;
        #pragma unroll
        for (int j = 0; j < H3N; ++j) h3out[j] = fmaf(hk, wr[j], h3out[j]);
    }
    #pragma unroll
    for (int j = 0; j < H3N; ++j) h3out[j] = fmaxf(h3out[j], 0.f);
}

__global__ __launch_bounds__(256) void fused_kernel(
    const float* __restrict__ x,
    const float* __restrict__ W1, const float* __restrict__ b1,
    const float* __restrict__ W2, const float* __restrict__ b2,
    const float* __restrict__ W3, const float* __restrict__ b3,
    const float* __restrict__ W_out, const float* __restrict__ b_out,
    const float* __restrict__ pqrs,
    float* __restrict__ y, int nrows) {
    const int row = blockIdx.x * 256 + threadIdx.x;
    if (row >= nrows) return;
    const float* __restrict__ xr = x + (size_t)row * NFEA;

    float out[32];
    tower(xr,       W1, b1, W2, b2, W3, b3, &out[0]);
    tower(xr + MID, W1, b1, W2, b2, W3, b3, &out[16]);

    // --- interaction: G[i][j] = tanh(oL*oR*P + oL*Q + oR*R + S), consumed
    //     on the fly into si (sum over j) and sj (sum over i).
    float si[16];
    #pragma unroll
    for (int i = 0; i < 16; ++i) si[i] = 0.f;
    float sj[16];
    #pragma unroll
    for (int j = 0; j < 16; ++j) {
        const float oR = out[16 + j];
        const float* __restrict__ Pr = pqrs +       j * 16;
        const float* __restrict__ Qr = pqrs + 256 + j * 16;
        const float* __restrict__ Rr = pqrs + 512 + j * 16;
        const float* __restrict__ Sr = pqrs + 768 + j * 16;
        float acc = 0.f;
        #pragma unroll
        for (int i = 0; i < 16; ++i) {
            const float t1 = fmaf(oR, Pr[i], Qr[i]);
            const float t2 = fmaf(oR, Rr[i], Sr[i]);
            const float g  = fast_tanh(fmaf(out[i], t1, t2));
            acc   += g;
            si[i] += g;
        }
        sj[j] = acc;
    }

    // lr = softmax(sj) scales out[0:16]; rl = softmax(si) scales out[16:32]
    {
        float mx = sj[0];
        #pragma unroll
        for (int i = 1; i < 16; ++i) mx = fmaxf(mx, sj[i]);
        float s = 0.f; float ex[16];
        #pragma unroll
        for (int i = 0; i < 16; ++i) { ex[i] = __expf(sj[i] - mx); s += ex[i]; }
        const float inv = __builtin_amdgcn_rcpf(s);
        #pragma unroll
        for (int i = 0; i < 16; ++i) out[i] *= ex[i] * inv;
    }
    {
        float mx = si[0];
        #pragma unroll
        for (int i = 1; i < 16; ++i) mx = fmaxf(mx, si[i]);
        float s = 0.f; float ex[16];
        #pragma unroll
        for (int i = 0; i < 16; ++i) { ex[i] = __expf(si[i] - mx); s += ex[i]; }
        const float inv = __builtin_amdgcn_rcpf(s);
        #pragma unroll
        for (int i = 0; i < 16; ++i) out[16 + i] *= ex[i] * inv;
    }

    // final projection (32x16) + relu
    float yv[16];
    #pragma unroll
    for (int o = 0; o < 16; ++o) yv[o] = b_out[o];
    #pragma unroll 4
    for (int c = 0; c < 32; ++c) {
        const float oc = out[c];
        const float* __restrict__ wr = W_out + c * 16;
        #pragma unroll
        for (int o = 0; o < 16; ++o) yv[o] = fmaf(oc, wr[o], yv[o]);
    }
    float* __restrict__ yo = y + (size_t)row * 16;
    #pragma unroll
    for (int q = 0; q < 4; ++q) {
        float4 v;
        v.x = fmaxf(yv[q * 4 + 0], 0.f);
        v.y = fmaxf(yv[q * 4 + 1], 0.f);
        v.z = fmaxf(yv[q * 4 + 2], 0.f);
        v.w = fmaxf(yv[q * 4 + 3], 0.f);
        *reinterpret_cast<float4*>(yo + q * 4) = v;
    }
}

extern "C" void kernel_launch(void* const* d_in, const int* in_sizes, int n_in,
                              void* d_out, int out_size, void* d_ws, size_t ws_size,
                              hipStream_t stream) {
    const float* x     = (const float*)d_in[0];
    const float* W1    = (const float*)d_in[1];
    const float* b1    = (const float*)d_in[2];
    const float* W2    = (const float*)d_in[3];
    const float* b2    = (const float*)d_in[4];
    const float* W3    = (const float*)d_in[5];
    const float* b3    = (const float*)d_in[6];
    const float* W_emb = (const float*)d_in[7];
    const float* b_emb = (const float*)d_in[8];
    const float* M     = (const float*)d_in[9];
    const float* W_out = (const float*)d_in[10];
    const float* b_out = (const float*)d_in[11];
    float* y    = (float*)d_out;
    float* pqrs = (float*)d_ws;   // 4 KB

    const int nrows = in_sizes[0] / NFEA;

    pqrs_kernel<<<1, 256, 0, stream>>>(W_emb, b_emb, M, pqrs);
    const int grid = (nrows + 255) / 256;
    fused_kernel<<<grid, 256, 0, stream>>>(x, W1, b1, W2, b2, W3, b3,
                                           W_out, b_out, pqrs, y, nrows);
}

// Round 2
// 290.568 us; speedup vs baseline: 1.8215x; 1.8215x over previous
//
#include <hip/hip_runtime.h>

constexpr int NFEA = 256;
constexpr int MID  = 128;
constexpr int H1N  = 64;
constexpr int H2N  = 32;
constexpr int H3N  = 16;

__device__ __forceinline__ float fast_tanh(float x) {
    // tanh(x) = 1 - 2/(exp(2x)+1); exp overflow/underflow give correct +-1
    float e = __expf(2.0f * x);
    float r = __builtin_amdgcn_rcpf(e + 1.0f);
    return fmaf(-2.0f, r, 1.0f);
}

// ---------------------------------------------------------------------------
// Precompute P,Q,R,S (16x16 each) into d_ws:
//   dot(l_i, M, r_j) = oL_i*oR_j*P[i][j] + oL_i*Q[i][j] + oR_j*R[i][j] + S[i][j]
// Layout: pqrs[0..255]=P (j*16+i), [256..511]=Q, [512..767]=R, [768..1023]=S.
// ---------------------------------------------------------------------------
__global__ void pqrs_kernel(const float* __restrict__ W_emb,
                            const float* __restrict__ b_emb,
                            const float* __restrict__ M,
                            float* __restrict__ pqrs) {
    const int t = threadIdx.x;
    if (t >= 256) return;
    const int j = t >> 4;   // right channel 16+j
    const int i = t & 15;   // left channel i

    float mr[8], mb[8];
    #pragma unroll
    for (int e = 0; e < 8; ++e) {
        float ar = 0.f, ab = 0.f;
        #pragma unroll
        for (int f = 0; f < 8; ++f) {
            const float m = M[e * 8 + f];
            ar = fmaf(m, W_emb[(16 + j) * 8 + f], ar);
            ab = fmaf(m, b_emb[(16 + j) * 8 + f], ab);
        }
        mr[e] = ar; mb[e] = ab;
    }
    float P = 0.f, Q = 0.f, R = 0.f, S = 0.f;
    #pragma unroll
    for (int e = 0; e < 8; ++e) {
        const float lw = W_emb[i * 8 + e];
        const float lb = b_emb[i * 8 + e];
        P = fmaf(lw, mr[e], P);
        Q = fmaf(lw, mb[e], Q);
        R = fmaf(lb, mr[e], R);
        S = fmaf(lb, mb[e], S);
    }
    pqrs[0 * 256 + j * 16 + i] = P;
    pqrs[1 * 256 + j * 16 + i] = Q;
    pqrs[2 * 256 + j * 16 + i] = R;
    pqrs[3 * 256 + j * 16 + i] = S;
}

// ---------------------------------------------------------------------------
// 2 threads per row: even lane = left tower, right lane = right tower.
// Weight indices are wave-uniform -> scalar loads. All register arrays are
// statically indexed (full unrolls). x loads double-buffered per 16-float
// chunk so ~1024 FMAs cover each load's latency.
// ---------------------------------------------------------------------------
__global__ __launch_bounds__(256, 4) void fused_kernel(
    const float* __restrict__ x,
    const float* __restrict__ W1, const float* __restrict__ b1,
    const float* __restrict__ W2, const float* __restrict__ b2,
    const float* __restrict__ W3, const float* __restrict__ b3,
    const float* __restrict__ W_out, const float* __restrict__ b_out,
    const float* __restrict__ pqrs,
    float* __restrict__ y, int nrows) {
    const int tid = blockIdx.x * 256 + threadIdx.x;
    const int row = tid >> 1;
    const int p   = tid & 1;            // 0 = left tower, 1 = right tower
    if (row >= nrows) return;
    const float* __restrict__ xs = x + (size_t)row * NFEA + p * MID;

    // ---- layer 1: 128 -> 64, chunks of 16 k's, double-buffered prefetch
    float h1[H1N];
    #pragma unroll
    for (int j = 0; j < H1N; ++j) h1[j] = b1[j];

    float4 a0 = *reinterpret_cast<const float4*>(xs + 0);
    float4 a1 = *reinterpret_cast<const float4*>(xs + 4);
    #pragma unroll 1
    for (int c = 0; c < 8; ++c) {
        // prefetch second half of this chunk
        const float4 b0v = *reinterpret_cast<const float4*>(xs + c * 16 + 8);
        const float4 b1v = *reinterpret_cast<const float4*>(xs + c * 16 + 12);
        {
            const float xk[8] = {a0.x, a0.y, a0.z, a0.w, a1.x, a1.y, a1.z, a1.w};
            #pragma unroll
            for (int kk = 0; kk < 8; ++kk) {
                const float xv = xk[kk];
                const float* __restrict__ wr = W1 + (c * 16 + kk) * H1N;
                #pragma unroll
                for (int j = 0; j < H1N; ++j) h1[j] = fmaf(xv, wr[j], h1[j]);
            }
        }
        // prefetch first half of next chunk
        if (c < 7) {
            a0 = *reinterpret_cast<const float4*>(xs + c * 16 + 16);
            a1 = *reinterpret_cast<const float4*>(xs + c * 16 + 20);
        }
        {
            const float xk[8] = {b0v.x, b0v.y, b0v.z, b0v.w, b1v.x, b1v.y, b1v.z, b1v.w};
            #pragma unroll
            for (int kk = 0; kk < 8; ++kk) {
                const float xv = xk[kk];
                const float* __restrict__ wr = W1 + (c * 16 + 8 + kk) * H1N;
                #pragma unroll
                for (int j = 0; j < H1N; ++j) h1[j] = fmaf(xv, wr[j], h1[j]);
            }
        }
    }

    // ---- layer 2: 64 -> 32 (relu folded into reads), fully static
    float h2[H2N];
    #pragma unroll
    for (int j = 0; j < H2N; ++j) h2[j] = b2[j];
    #pragma unroll
    for (int k = 0; k < H1N; ++k) {
        const float hk = fmaxf(h1[k], 0.f);
        const float* __restrict__ wr = W2 + k * H2N;
        #pragma unroll
        for (int j = 0; j < H2N; ++j) h2[j] = fmaf(hk, wr[j], h2[j]);
    }

    // ---- layer 3: 32 -> 16
    float o[H3N];
    #pragma unroll
    for (int j = 0; j < H3N; ++j) o[j] = b3[j];
    #pragma unroll
    for (int k = 0; k < H2N; ++k) {
        const float hk = fmaxf(h2[k], 0.f);
        const float* __restrict__ wr = W3 + k * H3N;
        #pragma unroll
        for (int j = 0; j < H3N; ++j) o[j] = fmaf(hk, wr[j], o[j]);
    }
    #pragma unroll
    for (int j = 0; j < H3N; ++j) o[j] = fmaxf(o[j], 0.f);

    // ---- exchange with partner lane: assemble (oL, oR) on both lanes
    float oL[16], oR[16];
    #pragma unroll
    for (int i = 0; i < 16; ++i) {
        const float oth = __shfl_xor(o[i], 1);
        oL[i] = p ? oth : o[i];
        oR[i] = p ? o[i] : oth;
    }

    // ---- interaction: G[i][j]=tanh(oL*oR*P + oL*Q + oR*R + S), on the fly
    float si[16];
    #pragma unroll
    for (int i = 0; i < 16; ++i) si[i] = 0.f;
    float sj[16];
    #pragma unroll
    for (int j = 0; j < 16; ++j) {
        const float r = oR[j];
        const float* __restrict__ Pr = pqrs +       j * 16;
        const float* __restrict__ Qr = pqrs + 256 + j * 16;
        const float* __restrict__ Rr = pqrs + 512 + j * 16;
        const float* __restrict__ Sr = pqrs + 768 + j * 16;
        float acc = 0.f;
        #pragma unroll
        for (int i = 0; i < 16; ++i) {
            const float t1 = fmaf(r, Pr[i], Qr[i]);
            const float t2 = fmaf(r, Rr[i], Sr[i]);
            const float g  = fast_tanh(fmaf(oL[i], t1, t2));
            acc   += g;
            si[i] += g;
        }
        sj[j] = acc;
    }

    // lr = softmax(sj) scales oL; rl = softmax(si) scales oR
    {
        float mx = sj[0];
        #pragma unroll
        for (int i = 1; i < 16; ++i) mx = fmaxf(mx, sj[i]);
        float s = 0.f; float ex[16];
        #pragma unroll
        for (int i = 0; i < 16; ++i) { ex[i] = __expf(sj[i] - mx); s += ex[i]; }
        const float inv = __builtin_amdgcn_rcpf(s);
        #pragma unroll
        for (int i = 0; i < 16; ++i) oL[i] *= ex[i] * inv;
    }
    {
        float mx = si[0];
        #pragma unroll
        for (int i = 1; i < 16; ++i) mx = fmaxf(mx, si[i]);
        float s = 0.f; float ex[16];
        #pragma unroll
        for (int i = 0; i < 16; ++i) { ex[i] = __expf(si[i] - mx); s += ex[i]; }
        const float inv = __builtin_amdgcn_rcpf(s);
        #pragma unroll
        for (int i = 0; i < 16; ++i) oR[i] *= ex[i] * inv;
    }

    // ---- final projection (32x16), computed redundantly; each lane stores 8
    float yv[16];
    #pragma unroll
    for (int oo = 0; oo < 16; ++oo) yv[oo] = b_out[oo];
    #pragma unroll
    for (int c = 0; c < 16; ++c) {
        const float cl = oL[c];
        const float cr = oR[c];
        const float* __restrict__ wl = W_out + c * 16;
        const float* __restrict__ wt = W_out + (16 + c) * 16;
        #pragma unroll
        for (int oo = 0; oo < 16; ++oo) {
            yv[oo] = fmaf(cl, wl[oo], yv[oo]);
            yv[oo] = fmaf(cr, wt[oo], yv[oo]);
        }
    }
    #pragma unroll
    for (int oo = 0; oo < 16; ++oo) yv[oo] = fmaxf(yv[oo], 0.f);

    float4 v0, v1;
    v0.x = p ? yv[ 8] : yv[0];  v0.y = p ? yv[ 9] : yv[1];
    v0.z = p ? yv[10] : yv[2];  v0.w = p ? yv[11] : yv[3];
    v1.x = p ? yv[12] : yv[4];  v1.y = p ? yv[13] : yv[5];
    v1.z = p ? yv[14] : yv[6];  v1.w = p ? yv[15] : yv[7];
    float* __restrict__ yo = y + (size_t)row * 16 + p * 8;
    *reinterpret_cast<float4*>(yo)     = v0;
    *reinterpret_cast<float4*>(yo + 4) = v1;
}

extern "C" void kernel_launch(void* const* d_in, const int* in_sizes, int n_in,
                              void* d_out, int out_size, void* d_ws, size_t ws_size,
                              hipStream_t stream) {
    const float* x     = (const float*)d_in[0];
    const float* W1    = (const float*)d_in[1];
    const float* b1    = (const float*)d_in[2];
    const float* W2    = (const float*)d_in[3];
    const float* b2    = (const float*)d_in[4];
    const float* W3    = (const float*)d_in[5];
    const float* b3    = (const float*)d_in[6];
    const float* W_emb = (const float*)d_in[7];
    const float* b_emb = (const float*)d_in[8];
    const float* M     = (const float*)d_in[9];
    const float* W_out = (const float*)d_in[10];
    const float* b_out = (const float*)d_in[11];
    float* y    = (float*)d_out;
    float* pqrs = (float*)d_ws;   // 4 KB

    const int nrows = in_sizes[0] / NFEA;

    pqrs_kernel<<<1, 256, 0, stream>>>(W_emb, b_emb, M, pqrs);
    const int grid = (2 * nrows + 255) / 256;
    fused_kernel<<<grid, 256, 0, stream>>>(x, W1, b1, W2, b2, W3, b3,
                                           W_out, b_out, pqrs, y, nrows);
}

// Round 4
// 152.437 us; speedup vs baseline: 3.4721x; 1.9062x over previous
//
#include <hip/hip_runtime.h>

typedef __attribute__((ext_vector_type(8))) short bf16x8;
typedef __attribute__((ext_vector_type(4))) float f32x4;

#define MFMA16(a, b, c) __builtin_amdgcn_mfma_f32_16x16x32_bf16(a, b, c, 0, 0, 0)

__device__ __forceinline__ unsigned short f2bf(float f) {
    unsigned u = __builtin_bit_cast(unsigned, f);
    u += 0x7FFFu + ((u >> 16) & 1u);          // RNE
    return (unsigned short)(u >> 16);
}
__device__ __forceinline__ float bf2f(unsigned short h) {
    return __builtin_bit_cast(float, (unsigned)h << 16);
}
__device__ __forceinline__ void split8(const float* v, bf16x8& hi, bf16x8& lo) {
    #pragma unroll
    for (int i = 0; i < 8; ++i) {
        unsigned short h = f2bf(v[i]);
        hi[i] = (short)h;
        lo[i] = (short)f2bf(v[i] - bf2f(h));
    }
}

__device__ __forceinline__ float fast_tanh(float x) {
    float e = __expf(2.0f * x);
    float r = __builtin_amdgcn_rcpf(e + 1.0f);
    return fmaf(-2.0f, r, 1.0f);
}

// ---------------------------------------------------------------------------
// Prep: pqrs (interaction constants) + fragment-ordered split-bf16 weights.
// B-fragment for 16x16x32: lane l holds B[kt*32+(l>>4)*8+i][n*16+(l&15)], i<8.
// w1 frag idx = ((kt*4+n)*64+lane)*8+i ; w2 idx = ((kt*2+n)*64+lane)*8+i ;
// w3 idx = lane*8+i.  wsm = w2h[2048] | w2l[2048] | w3h[512] | w3l[512].
// ---------------------------------------------------------------------------
__global__ void prep_kernel(const float* __restrict__ W1,
                            const float* __restrict__ W2,
                            const float* __restrict__ W3,
                            const float* __restrict__ W_emb,
                            const float* __restrict__ b_emb,
                            const float* __restrict__ M,
                            float* __restrict__ pqrs,
                            unsigned short* __restrict__ w1h,
                            unsigned short* __restrict__ w1l,
                            unsigned short* __restrict__ wsm) {
    const int t = threadIdx.x;
    // ---- pqrs: G(i,j) = tanh(oL*oR*P + oL*Q + oR*R + S)
    {
        const int j = t >> 4;
        const int i = t & 15;
        float mr[8], mb[8];
        #pragma unroll
        for (int e = 0; e < 8; ++e) {
            float ar = 0.f, ab = 0.f;
            #pragma unroll
            for (int f = 0; f < 8; ++f) {
                const float m = M[e * 8 + f];
                ar = fmaf(m, W_emb[(16 + j) * 8 + f], ar);
                ab = fmaf(m, b_emb[(16 + j) * 8 + f], ab);
            }
            mr[e] = ar; mb[e] = ab;
        }
        float P = 0.f, Q = 0.f, R = 0.f, S = 0.f;
        #pragma unroll
        for (int e = 0; e < 8; ++e) {
            const float lw = W_emb[i * 8 + e];
            const float lb = b_emb[i * 8 + e];
            P = fmaf(lw, mr[e], P);
            Q = fmaf(lw, mb[e], Q);
            R = fmaf(lb, mr[e], R);
            S = fmaf(lb, mb[e], S);
        }
        pqrs[0 * 256 + j * 16 + i] = P;
        pqrs[1 * 256 + j * 16 + i] = Q;
        pqrs[2 * 256 + j * 16 + i] = R;
        pqrs[3 * 256 + j * 16 + i] = S;
    }
    // ---- W1 fragments (128x64): 8192 elems, 32/thread
    for (int e = 0; e < 32; ++e) {
        const int idx = t * 32 + e;
        const int i = idx & 7, lane = (idx >> 3) & 63;
        const int n = (idx >> 9) & 3, kt = idx >> 11;
        const int k = kt * 32 + (lane >> 4) * 8 + i;
        const int c = n * 16 + (lane & 15);
        const float v = W1[k * 64 + c];
        const unsigned short h = f2bf(v);
        w1h[idx] = h;
        w1l[idx] = f2bf(v - bf2f(h));
    }
    // ---- W2 fragments (64x32): 2048 elems, 8/thread
    for (int e = 0; e < 8; ++e) {
        const int idx = t * 8 + e;
        const int i = idx & 7, lane = (idx >> 3) & 63;
        const int n = (idx >> 9) & 1, kt = (idx >> 10) & 1;
        const int k = kt * 32 + (lane >> 4) * 8 + i;
        const int c = n * 16 + (lane & 15);
        const float v = W2[k * 32 + c];
        const unsigned short h = f2bf(v);
        wsm[idx] = h;
        wsm[2048 + idx] = f2bf(v - bf2f(h));
    }
    // ---- W3 fragments (32x16): 512 elems, 2/thread
    for (int e = 0; e < 2; ++e) {
        const int idx = t * 2 + e;
        const int i = idx & 7, lane = (idx >> 3) & 63;
        const int k = (lane >> 4) * 8 + i;
        const int c = lane & 15;
        const float v = W3[k * 16 + c];
        const unsigned short h = f2bf(v);
        wsm[4096 + idx] = h;
        wsm[4608 + idx] = f2bf(v - bf2f(h));
    }
}

// ---------------------------------------------------------------------------
// Fused MFMA kernel. Block = 4 waves; wave = 64 tower-rows (4 tiles of 16);
// block = 256 tower-rows = 128 original rows. Towers via split-bf16 MFMA,
// LDS transposes between layers, register epilogue (2 lanes / row).
// ---------------------------------------------------------------------------
__global__ __launch_bounds__(256, 2) void fused_kernel(
    const float* __restrict__ x,
    const unsigned short* __restrict__ w1h,
    const unsigned short* __restrict__ w1l,
    const unsigned short* __restrict__ wsm,
    const float* __restrict__ b1, const float* __restrict__ b2,
    const float* __restrict__ b3,
    const float* __restrict__ pqrs,
    const float* __restrict__ W_out, const float* __restrict__ b_out,
    float* __restrict__ y) {
    __shared__ unsigned short s_wf[5120];      // w2h|w2l|w3h|w3l
    __shared__ float s_tr[4][16 * 68];         // per-wave transpose tile (pad 68)
    __shared__ float s_h3[4][64 * 20];         // per-wave h3 stash (pad 20)

    const int tid = threadIdx.x;
    {   // stage w2/w3 fragments: 5120 ushort = 2560 uint = 10 * 256
        const unsigned int* g = (const unsigned int*)wsm;
        unsigned int* s = (unsigned int*)s_wf;
        #pragma unroll
        for (int it = 0; it < 10; ++it) s[it * 256 + tid] = g[it * 256 + tid];
    }
    __syncthreads();

    const int l  = tid & 63;
    const int wv = tid >> 6;
    const int lm = l & 15;
    const int lg = l >> 4;

    const unsigned short* s_w2h = s_wf;
    const unsigned short* s_w2l = s_wf + 2048;
    const unsigned short* s_w3h = s_wf + 4096;
    const unsigned short* s_w3l = s_wf + 4608;

    float b1v[4], b2v[2];
    #pragma unroll
    for (int n = 0; n < 4; ++n) b1v[n] = b1[n * 16 + lm];
    #pragma unroll
    for (int n = 0; n < 2; ++n) b2v[n] = b2[n * 16 + lm];
    const float b3v = b3[lm];

    const long tr0 = (long)blockIdx.x * 256 + wv * 64;  // wave's first tower-row
    float* tb  = s_tr[wv];
    float* h3b = s_h3[wv];

    float4 xb[2][8];
    {
        const float* xp = x + (tr0 + lm) * 128 + lg * 8;
        #pragma unroll
        for (int kt = 0; kt < 4; ++kt) {
            xb[0][2 * kt]     = *(const float4*)(xp + kt * 32);
            xb[0][2 * kt + 1] = *(const float4*)(xp + kt * 32 + 4);
        }
    }

    #pragma unroll
    for (int tile = 0; tile < 4; ++tile) {
        const int cur = tile & 1, nxt = cur ^ 1;
        if (tile < 3) {   // prefetch next tile's x
            const float* xp = x + (tr0 + (tile + 1) * 16 + lm) * 128 + lg * 8;
            #pragma unroll
            for (int kt = 0; kt < 4; ++kt) {
                xb[nxt][2 * kt]     = *(const float4*)(xp + kt * 32);
                xb[nxt][2 * kt + 1] = *(const float4*)(xp + kt * 32 + 4);
            }
        }
        // ---- layer 1: (16x128)@(128x64), split-bf16
        f32x4 acc[4];
        #pragma unroll
        for (int n = 0; n < 4; ++n) acc[n] = f32x4{b1v[n], b1v[n], b1v[n], b1v[n]};
        #pragma unroll
        for (int kt = 0; kt < 4; ++kt) {
            const float4 a = xb[cur][2 * kt], b = xb[cur][2 * kt + 1];
            const float xv[8] = {a.x, a.y, a.z, a.w, b.x, b.y, b.z, b.w};
            bf16x8 xh, xl; split8(xv, xh, xl);
            #pragma unroll
            for (int n = 0; n < 4; ++n) {
                const int fo = ((kt * 4 + n) * 64 + l) * 8;
                const bf16x8 wh = *(const bf16x8*)(w1h + fo);
                const bf16x8 wl = *(const bf16x8*)(w1l + fo);
                acc[n] = MFMA16(xh, wh, acc[n]);
                acc[n] = MFMA16(xl, wh, acc[n]);
                acc[n] = MFMA16(xh, wl, acc[n]);
            }
        }
        // ---- transpose h1 via LDS (relu on write)
        #pragma unroll
        for (int n = 0; n < 4; ++n)
            #pragma unroll
            for (int r = 0; r < 4; ++r)
                tb[(lg * 4 + r) * 68 + n * 16 + lm] = fmaxf(acc[n][r], 0.f);
        // ---- layer 2: (16x64)@(64x32)
        f32x4 acc2[2];
        #pragma unroll
        for (int n = 0; n < 2; ++n) acc2[n] = f32x4{b2v[n], b2v[n], b2v[n], b2v[n]};
        #pragma unroll
        for (int kt = 0; kt < 2; ++kt) {
            const float* ap = tb + lm * 68 + kt * 32 + lg * 8;
            const float4 h0 = *(const float4*)(ap);
            const float4 h1 = *(const float4*)(ap + 4);
            const float hv[8] = {h0.x, h0.y, h0.z, h0.w, h1.x, h1.y, h1.z, h1.w};
            bf16x8 hh, hl; split8(hv, hh, hl);
            #pragma unroll
            for (int n = 0; n < 2; ++n) {
                const int fo = ((kt * 2 + n) * 64 + l) * 8;
                const bf16x8 wh = *(const bf16x8*)(s_w2h + fo);
                const bf16x8 wl = *(const bf16x8*)(s_w2l + fo);
                acc2[n] = MFMA16(hh, wh, acc2[n]);
                acc2[n] = MFMA16(hl, wh, acc2[n]);
                acc2[n] = MFMA16(hh, wl, acc2[n]);
            }
        }
        // ---- transpose h2 (reuse tb; same-wave LDS ordering is in-order)
        #pragma unroll
        for (int n = 0; n < 2; ++n)
            #pragma unroll
            for (int r = 0; r < 4; ++r)
                tb[(lg * 4 + r) * 68 + n * 16 + lm] = fmaxf(acc2[n][r], 0.f);
        // ---- layer 3: (16x32)@(32x16)
        f32x4 acc3 = f32x4{b3v, b3v, b3v, b3v};
        {
            const float* ap = tb + lm * 68 + lg * 8;
            const float4 h0 = *(const float4*)(ap);
            const float4 h1 = *(const float4*)(ap + 4);
            const float hv[8] = {h0.x, h0.y, h0.z, h0.w, h1.x, h1.y, h1.z, h1.w};
            bf16x8 hh, hl; split8(hv, hh, hl);
            const bf16x8 wh = *(const bf16x8*)(s_w3h + l * 8);
            const bf16x8 wl = *(const bf16x8*)(s_w3l + l * 8);
            acc3 = MFMA16(hh, wh, acc3);
            acc3 = MFMA16(hl, wh, acc3);
            acc3 = MFMA16(hh, wl, acc3);
        }
        // ---- stash h3 (relu)
        #pragma unroll
        for (int r = 0; r < 4; ++r)
            h3b[(tile * 16 + lg * 4 + r) * 20 + lm] = fmaxf(acc3[r], 0.f);
    }

    // ---- epilogue: lane l owns tower-row (tr0 + l); 2 lanes per original row
    const int p = l & 1;
    float o[16];
    {
        const float4* hp = (const float4*)(h3b + l * 20);
        const float4 t0 = hp[0], t1 = hp[1], t2 = hp[2], t3 = hp[3];
        o[0] = t0.x;  o[1] = t0.y;  o[2] = t0.z;  o[3] = t0.w;
        o[4] = t1.x;  o[5] = t1.y;  o[6] = t1.z;  o[7] = t1.w;
        o[8] = t2.x;  o[9] = t2.y;  o[10] = t2.z; o[11] = t2.w;
        o[12] = t3.x; o[13] = t3.y; o[14] = t3.z; o[15] = t3.w;
    }
    float oL[16], oR[16];
    #pragma unroll
    for (int i = 0; i < 16; ++i) {
        const float oth = __shfl_xor(o[i], 1);
        oL[i] = p ? oth : o[i];
        oR[i] = p ? o[i] : oth;
    }

    float si[16];
    #pragma unroll
    for (int i = 0; i < 16; ++i) si[i] = 0.f;
    float sj[16];
    #pragma unroll
    for (int j = 0; j < 16; ++j) {
        const float r = oR[j];
        const float* __restrict__ Pr = pqrs +       j * 16;
        const float* __restrict__ Qr = pqrs + 256 + j * 16;
        const float* __restrict__ Rr = pqrs + 512 + j * 16;
        const float* __restrict__ Sr = pqrs + 768 + j * 16;
        float accg = 0.f;
        #pragma unroll
        for (int i = 0; i < 16; ++i) {
            const float t1 = fmaf(r, Pr[i], Qr[i]);
            const float t2 = fmaf(r, Rr[i], Sr[i]);
            const float g  = fast_tanh(fmaf(oL[i], t1, t2));
            accg  += g;
            si[i] += g;
        }
        sj[j] = accg;
    }
    {
        float mx = sj[0];
        #pragma unroll
        for (int i = 1; i < 16; ++i) mx = fmaxf(mx, sj[i]);
        float s = 0.f; float ex[16];
        #pragma unroll
        for (int i = 0; i < 16; ++i) { ex[i] = __expf(sj[i] - mx); s += ex[i]; }
        const float inv = __builtin_amdgcn_rcpf(s);
        #pragma unroll
        for (int i = 0; i < 16; ++i) oL[i] *= ex[i] * inv;
    }
    {
        float mx = si[0];
        #pragma unroll
        for (int i = 1; i < 16; ++i) mx = fmaxf(mx, si[i]);
        float s = 0.f; float ex[16];
        #pragma unroll
        for (int i = 0; i < 16; ++i) { ex[i] = __expf(si[i] - mx); s += ex[i]; }
        const float inv = __builtin_amdgcn_rcpf(s);
        #pragma unroll
        for (int i = 0; i < 16; ++i) oR[i] *= ex[i] * inv;
    }

    float yv[16];
    #pragma unroll
    for (int oo = 0; oo < 16; ++oo) yv[oo] = b_out[oo];
    #pragma unroll
    for (int c = 0; c < 16; ++c) {
        const float cl = oL[c];
        const float cr = oR[c];
        const float* __restrict__ wl = W_out + c * 16;
        const float* __restrict__ wt = W_out + (16 + c) * 16;
        #pragma unroll
        for (int oo = 0; oo < 16; ++oo) {
            yv[oo] = fmaf(cl, wl[oo], yv[oo]);
            yv[oo] = fmaf(cr, wt[oo], yv[oo]);
        }
    }
    #pragma unroll
    for (int oo = 0; oo < 16; ++oo) yv[oo] = fmaxf(yv[oo], 0.f);

    float4 v0, v1;
    v0.x = p ? yv[8]  : yv[0]; v0.y = p ? yv[9]  : yv[1];
    v0.z = p ? yv[10] : yv[2]; v0.w = p ? yv[11] : yv[3];
    v1.x = p ? yv[12] : yv[4]; v1.y = p ? yv[13] : yv[5];
    v1.z = p ? yv[14] : yv[6]; v1.w = p ? yv[15] : yv[7];
    const long row = (tr0 >> 1) + (l >> 1);
    float* __restrict__ yo = y + row * 16 + p * 8;
    *reinterpret_cast<float4*>(yo)     = v0;
    *reinterpret_cast<float4*>(yo + 4) = v1;
}

extern "C" void kernel_launch(void* const* d_in, const int* in_sizes, int n_in,
                              void* d_out, int out_size, void* d_ws, size_t ws_size,
                              hipStream_t stream) {
    const float* x     = (const float*)d_in[0];
    const float* W1    = (const float*)d_in[1];
    const float* b1    = (const float*)d_in[2];
    const float* W2    = (const float*)d_in[3];
    const float* b2    = (const float*)d_in[4];
    const float* W3    = (const float*)d_in[5];
    const float* b3    = (const float*)d_in[6];
    const float* W_emb = (const float*)d_in[7];
    const float* b_emb = (const float*)d_in[8];
    const float* M     = (const float*)d_in[9];
    const float* W_out = (const float*)d_in[10];
    const float* b_out = (const float*)d_in[11];
    float* y = (float*)d_out;

    float* pqrs = (float*)d_ws;                                    // 4 KB
    unsigned short* w1h = (unsigned short*)((char*)d_ws + 4096);   // 16 KB
    unsigned short* w1l = w1h + 8192;                              // 16 KB
    unsigned short* wsm = w1l + 8192;                              // 10 KB

    const int nrows = in_sizes[0] / 256;

    prep_kernel<<<1, 256, 0, stream>>>(W1, W2, W3, W_emb, b_emb, M,
                                       pqrs, w1h, w1l, wsm);
    const int grid = nrows / 128;   // B = 262144 -> 2048 blocks
    fused_kernel<<<grid, 256, 0, stream>>>(x, w1h, w1l, wsm,
                                           b1, b2, b3, pqrs, W_out, b_out, y);
}

// Round 5
// 132.167 us; speedup vs baseline: 4.0046x; 1.1534x over previous
//
#include <hip/hip_runtime.h>

typedef __attribute__((ext_vector_type(8))) short bf16x8;
typedef __attribute__((ext_vector_type(4))) float f32x4;

#define MFMA16(a, b, c) __builtin_amdgcn_mfma_f32_16x16x32_bf16(a, b, c, 0, 0, 0)

__device__ __forceinline__ unsigned short f2bf(float f) {
    unsigned u = __builtin_bit_cast(unsigned, f);
    u += 0x7FFFu + ((u >> 16) & 1u);          // RNE
    return (unsigned short)(u >> 16);
}
__device__ __forceinline__ float bf2f(unsigned short h) {
    return __builtin_bit_cast(float, (unsigned)h << 16);
}

// split8 via v_cvt_pk_bf16_f32 (RNE, 2 elems/op): hi plane + bf16(residual)
__device__ __forceinline__ void split8(const float* v, bf16x8& hi, bf16x8& lo) {
    unsigned* hp = reinterpret_cast<unsigned*>(&hi);
    unsigned* lp = reinterpret_cast<unsigned*>(&lo);
    #pragma unroll
    for (int q = 0; q < 4; ++q) {
        const float a = v[2 * q], b = v[2 * q + 1];
        unsigned hpair;
        asm("v_cvt_pk_bf16_f32 %0, %1, %2" : "=v"(hpair) : "v"(a), "v"(b));
        const float ha = __builtin_bit_cast(float, hpair << 16);
        const float hb = __builtin_bit_cast(float, hpair & 0xFFFF0000u);
        const float ra = a - ha, rb = b - hb;
        unsigned lpair;
        asm("v_cvt_pk_bf16_f32 %0, %1, %2" : "=v"(lpair) : "v"(ra), "v"(rb));
        hp[q] = hpair;
        lp[q] = lpair;
    }
}

// ---------------------------------------------------------------------------
// Prep: pqrs (interaction constants, PRE-SCALED by 2*log2(e)) + fragment-
// ordered split-bf16 weights. B-frag 16x16x32: lane l holds
// B[kt*32+(l>>4)*8+i][n*16+(l&15)], i<8.
// wsm = w2h[2048] | w2l[2048] | w3h[512] | w3l[512].
// ---------------------------------------------------------------------------
__global__ void prep_kernel(const float* __restrict__ W1,
                            const float* __restrict__ W2,
                            const float* __restrict__ W3,
                            const float* __restrict__ W_emb,
                            const float* __restrict__ b_emb,
                            const float* __restrict__ M,
                            float* __restrict__ pqrs,
                            unsigned short* __restrict__ w1h,
                            unsigned short* __restrict__ w1l,
                            unsigned short* __restrict__ wsm) {
    const int t = threadIdx.x;
    const float C2 = 2.8853900817779268f;   // 2*log2(e)
    {
        const int j = t >> 4;
        const int i = t & 15;
        float mr[8], mb[8];
        #pragma unroll
        for (int e = 0; e < 8; ++e) {
            float ar = 0.f, ab = 0.f;
            #pragma unroll
            for (int f = 0; f < 8; ++f) {
                const float m = M[e * 8 + f];
                ar = fmaf(m, W_emb[(16 + j) * 8 + f], ar);
                ab = fmaf(m, b_emb[(16 + j) * 8 + f], ab);
            }
            mr[e] = ar; mb[e] = ab;
        }
        float P = 0.f, Q = 0.f, R = 0.f, S = 0.f;
        #pragma unroll
        for (int e = 0; e < 8; ++e) {
            const float lw = W_emb[i * 8 + e];
            const float lb = b_emb[i * 8 + e];
            P = fmaf(lw, mr[e], P);
            Q = fmaf(lw, mb[e], Q);
            R = fmaf(lb, mr[e], R);
            S = fmaf(lb, mb[e], S);
        }
        pqrs[0 * 256 + j * 16 + i] = C2 * P;
        pqrs[1 * 256 + j * 16 + i] = C2 * Q;
        pqrs[2 * 256 + j * 16 + i] = C2 * R;
        pqrs[3 * 256 + j * 16 + i] = C2 * S;
    }
    for (int e = 0; e < 32; ++e) {
        const int idx = t * 32 + e;
        const int i = idx & 7, lane = (idx >> 3) & 63;
        const int n = (idx >> 9) & 3, kt = idx >> 11;
        const int k = kt * 32 + (lane >> 4) * 8 + i;
        const int c = n * 16 + (lane & 15);
        const float v = W1[k * 64 + c];
        const unsigned short h = f2bf(v);
        w1h[idx] = h;
        w1l[idx] = f2bf(v - bf2f(h));
    }
    for (int e = 0; e < 8; ++e) {
        const int idx = t * 8 + e;
        const int i = idx & 7, lane = (idx >> 3) & 63;
        const int n = (idx >> 9) & 1, kt = (idx >> 10) & 1;
        const int k = kt * 32 + (lane >> 4) * 8 + i;
        const int c = n * 16 + (lane & 15);
        const float v = W2[k * 32 + c];
        const unsigned short h = f2bf(v);
        wsm[idx] = h;
        wsm[2048 + idx] = f2bf(v - bf2f(h));
    }
    for (int e = 0; e < 2; ++e) {
        const int idx = t * 2 + e;
        const int i = idx & 7, lane = (idx >> 3) & 63;
        const int k = (lane >> 4) * 8 + i;
        const int c = lane & 15;
        const float v = W3[k * 16 + c];
        const unsigned short h = f2bf(v);
        wsm[4096 + idx] = h;
        wsm[4608 + idx] = f2bf(v - bf2f(h));
    }
}

// ---------------------------------------------------------------------------
// Fused kernel. Wave = 128 tower-rows (8 tiles of 16) = 64 original rows.
// Epilogue: lane l owns ONE original row (tower-rows 2l, 2l+1) -> no
// redundancy, no shuffles, pqrs loads stay wave-uniform (scalar).
// h3 stash is transposed [col][tower_row], stride 130 (b64-aligned, 2-way).
// No __syncthreads anywhere (all LDS per-wave).
// ---------------------------------------------------------------------------
__global__ __launch_bounds__(256, 3) void fused_kernel(
    const float* __restrict__ x,
    const unsigned short* __restrict__ w1h,
    const unsigned short* __restrict__ w1l,
    const unsigned short* __restrict__ wsm,
    const float* __restrict__ b1, const float* __restrict__ b2,
    const float* __restrict__ b3,
    const float* __restrict__ pqrs,
    const float* __restrict__ W_out, const float* __restrict__ b_out,
    float* __restrict__ y) {
    __shared__ float s_tr[4][16 * 68];     // per-wave transpose tile
    __shared__ float s_h3[4][16 * 130];    // per-wave h3^T stash

    const int tid = threadIdx.x;
    const int l  = tid & 63;
    const int wv = tid >> 6;
    const int lm = l & 15;
    const int lg = l >> 4;

    const unsigned short* w2h = wsm;
    const unsigned short* w2l = wsm + 2048;
    const unsigned short* w3h = wsm + 4096;
    const unsigned short* w3l = wsm + 4608;

    float b1v[4], b2v[2];
    #pragma unroll
    for (int n = 0; n < 4; ++n) b1v[n] = b1[n * 16 + lm];
    #pragma unroll
    for (int n = 0; n < 2; ++n) b2v[n] = b2[n * 16 + lm];
    const float b3v = b3[lm];

    const long tr0 = (long)blockIdx.x * 512 + wv * 128;  // wave's first tower-row
    float* tb  = s_tr[wv];
    float* h3b = s_h3[wv];

    float4 xb[2][8];
    {
        const float* xp = x + (tr0 + lm) * 128 + lg * 8;
        #pragma unroll
        for (int kt = 0; kt < 4; ++kt) {
            xb[0][2 * kt]     = *(const float4*)(xp + kt * 32);
            xb[0][2 * kt + 1] = *(const float4*)(xp + kt * 32 + 4);
        }
    }

    #pragma unroll
    for (int tile = 0; tile < 8; ++tile) {
        const int cur = tile & 1, nxt = cur ^ 1;
        if (tile < 7) {   // prefetch next tile's x
            const float* xp = x + (tr0 + (tile + 1) * 16 + lm) * 128 + lg * 8;
            #pragma unroll
            for (int kt = 0; kt < 4; ++kt) {
                xb[nxt][2 * kt]     = *(const float4*)(xp + kt * 32);
                xb[nxt][2 * kt + 1] = *(const float4*)(xp + kt * 32 + 4);
            }
        }
        // ---- layer 1: (16x128)@(128x64), split-bf16
        f32x4 acc[4];
        #pragma unroll
        for (int n = 0; n < 4; ++n) acc[n] = f32x4{b1v[n], b1v[n], b1v[n], b1v[n]};
        #pragma unroll
        for (int kt = 0; kt < 4; ++kt) {
            const float4 a = xb[cur][2 * kt], b = xb[cur][2 * kt + 1];
            const float xv[8] = {a.x, a.y, a.z, a.w, b.x, b.y, b.z, b.w};
            bf16x8 xh, xl; split8(xv, xh, xl);
            #pragma unroll
            for (int n = 0; n < 4; ++n) {
                const int fo = ((kt * 4 + n) * 64 + l) * 8;
                const bf16x8 wh = *(const bf16x8*)(w1h + fo);
                const bf16x8 wl = *(const bf16x8*)(w1l + fo);
                acc[n] = MFMA16(xh, wh, acc[n]);
                acc[n] = MFMA16(xl, wh, acc[n]);
                acc[n] = MFMA16(xh, wl, acc[n]);
            }
        }
        // ---- transpose h1 via LDS (relu on write)
        #pragma unroll
        for (int n = 0; n < 4; ++n)
            #pragma unroll
            for (int r = 0; r < 4; ++r)
                tb[(lg * 4 + r) * 68 + n * 16 + lm] = fmaxf(acc[n][r], 0.f);
        // ---- layer 2: (16x64)@(64x32)
        f32x4 acc2[2];
        #pragma unroll
        for (int n = 0; n < 2; ++n) acc2[n] = f32x4{b2v[n], b2v[n], b2v[n], b2v[n]};
        #pragma unroll
        for (int kt = 0; kt < 2; ++kt) {
            const float* ap = tb + lm * 68 + kt * 32 + lg * 8;
            const float4 h0 = *(const float4*)(ap);
            const float4 h1 = *(const float4*)(ap + 4);
            const float hv[8] = {h0.x, h0.y, h0.z, h0.w, h1.x, h1.y, h1.z, h1.w};
            bf16x8 hh, hl; split8(hv, hh, hl);
            #pragma unroll
            for (int n = 0; n < 2; ++n) {
                const int fo = ((kt * 2 + n) * 64 + l) * 8;
                const bf16x8 wh = *(const bf16x8*)(w2h + fo);
                const bf16x8 wl = *(const bf16x8*)(w2l + fo);
                acc2[n] = MFMA16(hh, wh, acc2[n]);
                acc2[n] = MFMA16(hl, wh, acc2[n]);
                acc2[n] = MFMA16(hh, wl, acc2[n]);
            }
        }
        // ---- transpose h2 (reuse tb; same-wave LDS ordering is in-order)
        #pragma unroll
        for (int n = 0; n < 2; ++n)
            #pragma unroll
            for (int r = 0; r < 4; ++r)
                tb[(lg * 4 + r) * 68 + n * 16 + lm] = fmaxf(acc2[n][r], 0.f);
        // ---- layer 3: (16x32)@(32x16)
        f32x4 acc3 = f32x4{b3v, b3v, b3v, b3v};
        {
            const float* ap = tb + lm * 68 + lg * 8;
            const float4 h0 = *(const float4*)(ap);
            const float4 h1 = *(const float4*)(ap + 4);
            const float hv[8] = {h0.x, h0.y, h0.z, h0.w, h1.x, h1.y, h1.z, h1.w};
            bf16x8 hh, hl; split8(hv, hh, hl);
            const bf16x8 wh = *(const bf16x8*)(w3h + l * 8);
            const bf16x8 wl = *(const bf16x8*)(w3l + l * 8);
            acc3 = MFMA16(hh, wh, acc3);
            acc3 = MFMA16(hl, wh, acc3);
            acc3 = MFMA16(hh, wl, acc3);
        }
        // ---- stash h3 transposed: h3b[col=lm][row = tile*16+lg*4+r] (relu)
        #pragma unroll
        for (int r = 0; r < 4; ++r)
            h3b[lm * 130 + tile * 16 + lg * 4 + r] = fmaxf(acc3[r], 0.f);
    }

    // ---- epilogue: lane l owns original row (tr0>>1)+l; towers 2l, 2l+1
    float oL[16], oR[16];
    #pragma unroll
    for (int c = 0; c < 16; ++c) {
        const float2 v = *(const float2*)(h3b + c * 130 + 2 * l);
        oL[c] = v.x;
        oR[c] = v.y;
    }

    // interaction: z' = 2*log2e*(oL*oR*P + oL*Q + oR*R + S) [scale folded in
    // prep]; g = 1 - 2*rcp(2^z' + 1); accumulate rc, fix up 16-2*sum at end
    float sir[16];
    #pragma unroll
    for (int i = 0; i < 16; ++i) sir[i] = 0.f;
    float sjv[16];
    #pragma unroll
    for (int j = 0; j < 16; ++j) {
        const float r = oR[j];
        const float* __restrict__ Pr = pqrs +       j * 16;
        const float* __restrict__ Qr = pqrs + 256 + j * 16;
        const float* __restrict__ Rr = pqrs + 512 + j * 16;
        const float* __restrict__ Sr = pqrs + 768 + j * 16;
        float accr = 0.f;
        #pragma unroll
        for (int i = 0; i < 16; ++i) {
            const float t1 = fmaf(r, Pr[i], Qr[i]);
            const float t2 = fmaf(r, Rr[i], Sr[i]);
            const float z  = fmaf(oL[i], t1, t2);
            const float e  = __builtin_amdgcn_exp2f(z);
            const float rc = __builtin_amdgcn_rcpf(e + 1.0f);
            accr   += rc;
            sir[i] += rc;
        }
        sjv[j] = accr;
    }
    // sj[j] = 16 - 2*sum(rc); si[i] likewise
    #pragma unroll
    for (int i = 0; i < 16; ++i) {
        sjv[i] = fmaf(-2.f, sjv[i], 16.f);
        sir[i] = fmaf(-2.f, sir[i], 16.f);
    }

    {   // lr = softmax(sj) scales oL
        float mx = sjv[0];
        #pragma unroll
        for (int i = 1; i < 16; ++i) mx = fmaxf(mx, sjv[i]);
        float s = 0.f; float ex[16];
        #pragma unroll
        for (int i = 0; i < 16; ++i) { ex[i] = __expf(sjv[i] - mx); s += ex[i]; }
        const float inv = __builtin_amdgcn_rcpf(s);
        #pragma unroll
        for (int i = 0; i < 16; ++i) oL[i] *= ex[i] * inv;
    }
    {   // rl = softmax(si) scales oR
        float mx = sir[0];
        #pragma unroll
        for (int i = 1; i < 16; ++i) mx = fmaxf(mx, sir[i]);
        float s = 0.f; float ex[16];
        #pragma unroll
        for (int i = 0; i < 16; ++i) { ex[i] = __expf(sir[i] - mx); s += ex[i]; }
        const float inv = __builtin_amdgcn_rcpf(s);
        #pragma unroll
        for (int i = 0; i < 16; ++i) oR[i] *= ex[i] * inv;
    }

    float yv[16];
    #pragma unroll
    for (int oo = 0; oo < 16; ++oo) yv[oo] = b_out[oo];
    #pragma unroll
    for (int c = 0; c < 16; ++c) {
        const float cl = oL[c];
        const float cr = oR[c];
        const float* __restrict__ wl = W_out + c * 16;
        const float* __restrict__ wt = W_out + (16 + c) * 16;
        #pragma unroll
        for (int oo = 0; oo < 16; ++oo) {
            yv[oo] = fmaf(cl, wl[oo], yv[oo]);
            yv[oo] = fmaf(cr, wt[oo], yv[oo]);
        }
    }

    float* __restrict__ yo = y + ((tr0 >> 1) + l) * 16;
    #pragma unroll
    for (int q = 0; q < 4; ++q) {
        float4 v;
        v.x = fmaxf(yv[q * 4 + 0], 0.f);
        v.y = fmaxf(yv[q * 4 + 1], 0.f);
        v.z = fmaxf(yv[q * 4 + 2], 0.f);
        v.w = fmaxf(yv[q * 4 + 3], 0.f);
        *reinterpret_cast<float4*>(yo + q * 4) = v;
    }
}

extern "C" void kernel_launch(void* const* d_in, const int* in_sizes, int n_in,
                              void* d_out, int out_size, void* d_ws, size_t ws_size,
                              hipStream_t stream) {
    const float* x     = (const float*)d_in[0];
    const float* W1    = (const float*)d_in[1];
    const float* b1    = (const float*)d_in[2];
    const float* W2    = (const float*)d_in[3];
    const float* b2    = (const float*)d_in[4];
    const float* W3    = (const float*)d_in[5];
    const float* b3    = (const float*)d_in[6];
    const float* W_emb = (const float*)d_in[7];
    const float* b_emb = (const float*)d_in[8];
    const float* M     = (const float*)d_in[9];
    const float* W_out = (const float*)d_in[10];
    const float* b_out = (const float*)d_in[11];
    float* y = (float*)d_out;

    float* pqrs = (float*)d_ws;                                    // 4 KB
    unsigned short* w1h = (unsigned short*)((char*)d_ws + 4096);   // 16 KB
    unsigned short* w1l = w1h + 8192;                              // 16 KB
    unsigned short* wsm = w1l + 8192;                              // 10 KB

    const int nrows = in_sizes[0] / 256;

    prep_kernel<<<1, 256, 0, stream>>>(W1, W2, W3, W_emb, b_emb, M,
                                       pqrs, w1h, w1l, wsm);
    const int grid = nrows / 256;   // B = 262144 -> 1024 blocks
    fused_kernel<<<grid, 256, 0, stream>>>(x, w1h, w1l, wsm,
                                           b1, b2, b3, pqrs, W_out, b_out, y);
}